// Round 14
// baseline (499.452 us; speedup 1.0000x reference)
//
#include <hip/hip_runtime.h>

// ---------------------------------------------------------------------------
// GraphSAGE 3-layer, bf16 pipeline. Round 14 = round 13 (296us) plus
// split-GEMM overlap on layers 0/1:
//   K_a (co-grid): agg256(h->h1)  ||  gemmR: r = H@Wr + b   (independent!)
//   K_b:           h_next = relu(Agg@Wl + r)
// The H@Wr half never depended on aggregation; hiding it under agg's
// service-rate-bound window (~55us) removes ~13us/layer of serial time.
// agg256 held at measured structural floor (invariant across 5 variants).
// ---------------------------------------------------------------------------

typedef short bf16x8 __attribute__((ext_vector_type(8)));
typedef float f32x4 __attribute__((ext_vector_type(4)));

__device__ __forceinline__ unsigned short f2bf(float f) {
    unsigned int b = __float_as_uint(f);
    b += 0x7fffu + ((b >> 16) & 1u);
    return (unsigned short)(b >> 16);
}
__device__ __forceinline__ float bflo(unsigned int u) { return __uint_as_float(u << 16); }
__device__ __forceinline__ float bfhi(unsigned int u) { return __uint_as_float(u & 0xffff0000u); }
__device__ __forceinline__ float bf2f(unsigned short u) { return __uint_as_float((unsigned)u << 16); }

__device__ __forceinline__ void gload_lds16(const void* g, void* l) {
    __builtin_amdgcn_global_load_lds(
        (const __attribute__((address_space(1))) void*)g,
        (__attribute__((address_space(3))) void*)l, 16, 0, 0);
}

// ---------------- combined fill_pos + prep ----------------
// blocks [0, nPosBlk): pos[e] = atomicAdd(cursor[dst[e]]) (cursor ends = deg)
// blocks [nPosBlk, ...): x->bf16 cvt + 6 weight transposes (split l/r)
__global__ void fillpos_prep_kernel(
        const int* __restrict__ ei, int* __restrict__ cursor, int* __restrict__ pos,
        int E, int nPosBlk,
        const float* __restrict__ x, unsigned short* __restrict__ xb,
        const float* __restrict__ Wl0, unsigned short* __restrict__ BT0l,
        const float* __restrict__ Wr0, unsigned short* __restrict__ BT0r,
        const float* __restrict__ Wl1, unsigned short* __restrict__ BT1l,
        const float* __restrict__ Wr1, unsigned short* __restrict__ BT1r,
        const float* __restrict__ Wl2, unsigned short* __restrict__ BT2l,
        const float* __restrict__ Wr2, unsigned short* __restrict__ BT2r,
        int n4) {
    if (blockIdx.x < nPosBlk) {
        int e = blockIdx.x * 256 + threadIdx.x;
        if (e < E) pos[e] = atomicAdd(&cursor[ei[E + e]], 1);
        return;
    }
    int t = (blockIdx.x - nPosBlk) * 256 + threadIdx.x;
    if (t < n4) {
        float4 v = ((const float4*)x)[t];
        ushort4 o;
        o.x = f2bf(v.x); o.y = f2bf(v.y); o.z = f2bf(v.z); o.w = f2bf(v.w);
        ((ushort4*)xb)[t] = o;
        return;
    }
    t -= n4;
    if (t < 65536) { int k = t >> 8, n = t & 255; BT0l[(size_t)n * 256 + k] = f2bf(Wl0[(size_t)k * 256 + n]); return; }
    t -= 65536;
    if (t < 65536) { int k = t >> 8, n = t & 255; BT0r[(size_t)n * 256 + k] = f2bf(Wr0[(size_t)k * 256 + n]); return; }
    t -= 65536;
    if (t < 65536) { int k = t >> 8, n = t & 255; BT1l[(size_t)n * 256 + k] = f2bf(Wl1[(size_t)k * 256 + n]); return; }
    t -= 65536;
    if (t < 65536) { int k = t >> 8, n = t & 255; BT1r[(size_t)n * 256 + k] = f2bf(Wr1[(size_t)k * 256 + n]); return; }
    t -= 65536;
    if (t < 16384) { int k = t >> 6, n = t & 63; BT2l[(size_t)n * 256 + k] = f2bf(Wl2[(size_t)k * 64 + n]); return; }
    t -= 16384;
    if (t < 16384) { int k = t >> 6, n = t & 63; BT2r[(size_t)n * 256 + k] = f2bf(Wr2[(size_t)k * 64 + n]); }
}

// ---------------- CSR scan ----------------
__global__ __launch_bounds__(1024) void scan1_kernel(
        const int* __restrict__ deg, int* __restrict__ incl, int* __restrict__ bsum, int n) {
    __shared__ int wsum[16];
    __shared__ int woff[16];
    const int tid = threadIdx.x, lane = tid & 63, wid = tid >> 6;
    int i = blockIdx.x * 1024 + tid;
    int x = (i < n) ? deg[i] : 0;
    #pragma unroll
    for (int off = 1; off < 64; off <<= 1) {
        int t = __shfl_up(x, off, 64);
        if (lane >= off) x += t;
    }
    if (lane == 63) wsum[wid] = x;
    __syncthreads();
    if (tid == 0) {
        int s = 0;
        #pragma unroll
        for (int w = 0; w < 16; ++w) { woff[w] = s; s += wsum[w]; }
        bsum[blockIdx.x] = s;
    }
    __syncthreads();
    if (i < n) incl[i] = x + woff[wid];
}

__global__ void scan3_kernel(const int* __restrict__ incl, const int* __restrict__ bsum,
                             int* __restrict__ row_ptr, int n, int nb) {
    __shared__ int off_s;
    const int chunk = blockIdx.x >> 2;
    if (threadIdx.x < 64) {
        int lane = threadIdx.x;
        int v = (lane < chunk && lane < nb) ? bsum[lane] : 0;
        #pragma unroll
        for (int m = 1; m < 64; m <<= 1) v += __shfl_xor(v, m, 64);
        if (lane == 0) off_s = v;
    }
    __syncthreads();
    int i = blockIdx.x * 256 + threadIdx.x;
    if (i == 0) row_ptr[0] = 0;
    if (i < n) row_ptr[i + 1] = incl[i] + off_s;
}

__global__ void fill_scatter_kernel(const int* __restrict__ ei, const int* __restrict__ pos,
                                    const int* __restrict__ row_ptr, int* __restrict__ col, int E) {
    int e = blockIdx.x * blockDim.x + threadIdx.x;
    if (e < E) {
        int d = ei[E + e];
        col[row_ptr[d] + pos[e]] = ei[e];
    }
}

// ---------------- K_a: co-grid agg256 || gemmR ----------------
// blocks [0, aggGrid): agg256 hsrc -> aggdst (proven r4 structure)
// blocks [aggGrid, aggGrid+gx): r = hsrc@BTr + bias (bf16, no relu)
__global__ __launch_bounds__(256, 2) void agg_gemmR_kernel(
        const unsigned short* __restrict__ hsrc, const int* __restrict__ row_ptr,
        const int* __restrict__ col, unsigned short* __restrict__ aggdst,
        const unsigned short* __restrict__ BTr, const float* __restrict__ bias,
        unsigned short* __restrict__ r, int n, int aggGrid, int M) {
    __shared__ unsigned short As[128 * 32];
    __shared__ unsigned short Bs[256 * 32];

    if (blockIdx.x < aggGrid) {
        // ---- aggregation path ----
        int node = blockIdx.x * 4 + (threadIdx.x >> 6);
        int lane = threadIdx.x & 63;
        if (node >= n) return;
        const int start = row_ptr[node], end = row_ptr[node + 1];
        const int half = lane >> 5;
        const int fo = (lane & 31) * 8;
        float a[8] = {0.f, 0.f, 0.f, 0.f, 0.f, 0.f, 0.f, 0.f};
        int eb = start;
        for (; eb + 4 <= end; eb += 4) {
            int e0 = eb + half, e1 = eb + 2 + half;
            uint4 v0 = *(const uint4*)(hsrc + (size_t)col[e0] * 256 + fo);
            uint4 v1 = *(const uint4*)(hsrc + (size_t)col[e1] * 256 + fo);
            a[0] += bflo(v0.x) + bflo(v1.x); a[1] += bfhi(v0.x) + bfhi(v1.x);
            a[2] += bflo(v0.y) + bflo(v1.y); a[3] += bfhi(v0.y) + bfhi(v1.y);
            a[4] += bflo(v0.z) + bflo(v1.z); a[5] += bfhi(v0.z) + bfhi(v1.z);
            a[6] += bflo(v0.w) + bflo(v1.w); a[7] += bfhi(v0.w) + bfhi(v1.w);
        }
        for (; eb < end; eb += 2) {
            int e = eb + half;
            if (e < end) {
                uint4 v = *(const uint4*)(hsrc + (size_t)col[e] * 256 + fo);
                a[0] += bflo(v.x); a[1] += bfhi(v.x);
                a[2] += bflo(v.y); a[3] += bfhi(v.y);
                a[4] += bflo(v.z); a[5] += bfhi(v.z);
                a[6] += bflo(v.w); a[7] += bfhi(v.w);
            }
        }
        #pragma unroll
        for (int i = 0; i < 8; ++i) a[i] += __shfl_xor(a[i], 32, 64);
        int d = end - start;
        float inv = 1.0f / (float)(d > 1 ? d : 1);
        if (lane < 32) {
            ushort4 o0, o1;
            o0.x = f2bf(a[0] * inv); o0.y = f2bf(a[1] * inv);
            o0.z = f2bf(a[2] * inv); o0.w = f2bf(a[3] * inv);
            o1.x = f2bf(a[4] * inv); o1.y = f2bf(a[5] * inv);
            o1.z = f2bf(a[6] * inv); o1.w = f2bf(a[7] * inv);
            *(ushort4*)(aggdst + (size_t)node * 256 + fo) = o0;
            *(ushort4*)(aggdst + (size_t)node * 256 + fo + 4) = o1;
        }
        return;
    }

    // ---- gemmR path: r = hsrc@BTr + bias ----
    const int tid = threadIdx.x;
    const int lane = tid & 63;
    const int wid = tid >> 6;
    const int wr = wid >> 1, wc = wid & 1;
    const int row0 = (blockIdx.x - aggGrid) * 128;

    f32x4 acc[4][8];
    #pragma unroll
    for (int i = 0; i < 4; ++i)
        #pragma unroll
        for (int j = 0; j < 8; ++j) acc[i][j] = (f32x4){0.f, 0.f, 0.f, 0.f};

    const int rA = tid >> 2;
    const int kc = (tid & 3) * 8;

    for (int ks = 0; ks < 8; ++ks) {
        const int ka = ks * 32;
        #pragma unroll
        for (int i = 0; i < 2; ++i)
            gload_lds16(hsrc + (size_t)(row0 + rA + i * 64) * 256 + ka + kc,
                        As + (size_t)i * 2048 + tid * 8);
        #pragma unroll
        for (int i = 0; i < 4; ++i)
            gload_lds16(BTr + (size_t)(rA + i * 64) * 256 + ka + kc,
                        Bs + (size_t)i * 2048 + tid * 8);
        __syncthreads();

        bf16x8 a[4], b[8];
        #pragma unroll
        for (int tm = 0; tm < 4; ++tm)
            a[tm] = *(const bf16x8*)&As[(wr * 64 + tm * 16 + (lane & 15)) * 32 + (lane >> 4) * 8];
        #pragma unroll
        for (int tn = 0; tn < 8; ++tn)
            b[tn] = *(const bf16x8*)&Bs[(wc * 128 + tn * 16 + (lane & 15)) * 32 + (lane >> 4) * 8];
        #pragma unroll
        for (int tm = 0; tm < 4; ++tm)
            #pragma unroll
            for (int tn = 0; tn < 8; ++tn)
                acc[tm][tn] = __builtin_amdgcn_mfma_f32_16x16x32_bf16(a[tm], b[tn], acc[tm][tn], 0, 0, 0);
        __syncthreads();
    }

    #pragma unroll
    for (int tn = 0; tn < 8; ++tn) {
        int colg = wc * 128 + tn * 16 + (lane & 15);
        float bv = bias[colg];
        #pragma unroll
        for (int tm = 0; tm < 4; ++tm) {
            #pragma unroll
            for (int rr = 0; rr < 4; ++rr) {
                int row = row0 + wr * 64 + tm * 16 + (lane >> 4) * 4 + rr;
                if (row < M) r[(size_t)row * 256 + colg] = f2bf(acc[tm][tn][rr] + bv);
            }
        }
    }
}

// ---------------- K_b: h_next = relu(Agg@BTl + r) ----------------
__global__ __launch_bounds__(256, 2) void gemmL_kernel(
        const unsigned short* __restrict__ Agg, const unsigned short* __restrict__ BTl,
        const unsigned short* __restrict__ r, unsigned short* __restrict__ Cout, int M) {
    __shared__ unsigned short As[128 * 32];
    __shared__ unsigned short Bs[256 * 32];
    const int tid = threadIdx.x;
    const int lane = tid & 63;
    const int wid = tid >> 6;
    const int wr = wid >> 1, wc = wid & 1;
    const int row0 = blockIdx.x * 128;

    f32x4 acc[4][8];
    #pragma unroll
    for (int i = 0; i < 4; ++i)
        #pragma unroll
        for (int j = 0; j < 8; ++j) acc[i][j] = (f32x4){0.f, 0.f, 0.f, 0.f};

    const int rA = tid >> 2;
    const int kc = (tid & 3) * 8;

    for (int ks = 0; ks < 8; ++ks) {
        const int ka = ks * 32;
        #pragma unroll
        for (int i = 0; i < 2; ++i)
            gload_lds16(Agg + (size_t)(row0 + rA + i * 64) * 256 + ka + kc,
                        As + (size_t)i * 2048 + tid * 8);
        #pragma unroll
        for (int i = 0; i < 4; ++i)
            gload_lds16(BTl + (size_t)(rA + i * 64) * 256 + ka + kc,
                        Bs + (size_t)i * 2048 + tid * 8);
        __syncthreads();

        bf16x8 a[4], b[8];
        #pragma unroll
        for (int tm = 0; tm < 4; ++tm)
            a[tm] = *(const bf16x8*)&As[(wr * 64 + tm * 16 + (lane & 15)) * 32 + (lane >> 4) * 8];
        #pragma unroll
        for (int tn = 0; tn < 8; ++tn)
            b[tn] = *(const bf16x8*)&Bs[(wc * 128 + tn * 16 + (lane & 15)) * 32 + (lane >> 4) * 8];
        #pragma unroll
        for (int tm = 0; tm < 4; ++tm)
            #pragma unroll
            for (int tn = 0; tn < 8; ++tn)
                acc[tm][tn] = __builtin_amdgcn_mfma_f32_16x16x32_bf16(a[tm], b[tn], acc[tm][tn], 0, 0, 0);
        __syncthreads();
    }

    #pragma unroll
    for (int tn = 0; tn < 8; ++tn) {
        int colg = wc * 128 + tn * 16 + (lane & 15);
        #pragma unroll
        for (int tm = 0; tm < 4; ++tm) {
            #pragma unroll
            for (int rr = 0; rr < 4; ++rr) {
                int row = row0 + wr * 64 + tm * 16 + (lane >> 4) * 4 + rr;
                if (row < M) {
                    float v = acc[tm][tn][rr] + bf2f(r[(size_t)row * 256 + colg]);
                    Cout[(size_t)row * 256 + colg] = f2bf(fmaxf(v, 0.f));
                }
            }
        }
    }
}

// ---------------- aggregation, 64-dim, in-place add into out ----------------
__global__ __launch_bounds__(256) void agg64_add_kernel(
        const unsigned short* __restrict__ p, const int* __restrict__ row_ptr,
        const int* __restrict__ col, float* __restrict__ out, int n) {
    int node = blockIdx.x * 4 + (threadIdx.x >> 6);
    int lane = threadIdx.x & 63;
    if (node >= n) return;
    const int start = row_ptr[node], end = row_ptr[node + 1];
    const int g = lane >> 4;
    const int fo = (lane & 15) * 4;
    float a0 = 0.f, a1 = 0.f, a2 = 0.f, a3 = 0.f;
    int eb = start;
    for (; eb + 8 <= end; eb += 8) {
        int e0 = eb + g, e1 = eb + 4 + g;
        uint2 v0 = *(const uint2*)(p + (size_t)col[e0] * 64 + fo);
        uint2 v1 = *(const uint2*)(p + (size_t)col[e1] * 64 + fo);
        a0 += bflo(v0.x) + bflo(v1.x); a1 += bfhi(v0.x) + bfhi(v1.x);
        a2 += bflo(v0.y) + bflo(v1.y); a3 += bfhi(v0.y) + bfhi(v1.y);
    }
    for (; eb < end; eb += 4) {
        int e = eb + g;
        if (e < end) {
            uint2 v = *(const uint2*)(p + (size_t)col[e] * 64 + fo);
            a0 += bflo(v.x); a1 += bfhi(v.x);
            a2 += bflo(v.y); a3 += bfhi(v.y);
        }
    }
    #pragma unroll
    for (int m = 16; m <= 32; m <<= 1) {
        a0 += __shfl_xor(a0, m, 64);
        a1 += __shfl_xor(a1, m, 64);
        a2 += __shfl_xor(a2, m, 64);
        a3 += __shfl_xor(a3, m, 64);
    }
    int d = end - start;
    float inv = 1.0f / (float)(d > 1 ? d : 1);
    if (lane < 16) {
        float* dst = out + (size_t)node * 64 + fo;
        float4 base = *(float4*)dst;
        float4 o = make_float4(base.x + a0 * inv, base.y + a1 * inv,
                               base.z + a2 * inv, base.w + a3 * inv);
        *(float4*)dst = o;
    }
}

// ---------------- layer-2 dual-B GEMM (BM=128) ----------------
__global__ __launch_bounds__(256, 2) void gemm2_dual_kernel(
        const unsigned short* __restrict__ A,     // h3 [Mpad][256]
        const unsigned short* __restrict__ BTl,   // [64][256]
        const unsigned short* __restrict__ BTr,   // [64][256]
        const float* __restrict__ bias,           // [64]
        unsigned short* __restrict__ P2,          // [Mpad][64] bf16
        float* __restrict__ Out, int M) {
    __shared__ unsigned short As[128 * 32];
    __shared__ unsigned short Bl[64 * 32];
    __shared__ unsigned short Br[64 * 32];
    const int tid = threadIdx.x;
    const int lane = tid & 63;
    const int wid = tid >> 6;
    const int wr = wid >> 1, wc = wid & 1;
    const int row0 = blockIdx.x * 128;

    f32x4 accL[4][2], accR[4][2];
    #pragma unroll
    for (int i = 0; i < 4; ++i)
        #pragma unroll
        for (int j = 0; j < 2; ++j) {
            accL[i][j] = (f32x4){0.f, 0.f, 0.f, 0.f};
            accR[i][j] = (f32x4){0.f, 0.f, 0.f, 0.f};
        }

    const int rA = tid >> 2;
    const int kc = (tid & 3) * 8;

    for (int ks = 0; ks < 8; ++ks) {
        const int ka = ks * 32;
        #pragma unroll
        for (int i = 0; i < 2; ++i) {
            const unsigned short* g = A + (size_t)(row0 + rA + i * 64) * 256 + ka + kc;
            gload_lds16(g, As + (size_t)i * 2048 + tid * 8);
        }
        gload_lds16(BTl + (size_t)rA * 256 + ka + kc, Bl + tid * 8);
        gload_lds16(BTr + (size_t)rA * 256 + ka + kc, Br + tid * 8);
        __syncthreads();

        bf16x8 a[4], bl[2], br[2];
        #pragma unroll
        for (int tm = 0; tm < 4; ++tm)
            a[tm] = *(const bf16x8*)&As[(wr * 64 + tm * 16 + (lane & 15)) * 32 + (lane >> 4) * 8];
        #pragma unroll
        for (int tn = 0; tn < 2; ++tn) {
            int bi = (wc * 32 + tn * 16 + (lane & 15)) * 32 + (lane >> 4) * 8;
            bl[tn] = *(const bf16x8*)&Bl[bi];
            br[tn] = *(const bf16x8*)&Br[bi];
        }
        #pragma unroll
        for (int tm = 0; tm < 4; ++tm)
            #pragma unroll
            for (int tn = 0; tn < 2; ++tn) {
                accL[tm][tn] = __builtin_amdgcn_mfma_f32_16x16x32_bf16(a[tm], bl[tn], accL[tm][tn], 0, 0, 0);
                accR[tm][tn] = __builtin_amdgcn_mfma_f32_16x16x32_bf16(a[tm], br[tn], accR[tm][tn], 0, 0, 0);
            }
        __syncthreads();
    }

    #pragma unroll
    for (int tn = 0; tn < 2; ++tn) {
        int colg = wc * 32 + tn * 16 + (lane & 15);
        float bv = bias[colg];
        #pragma unroll
        for (int tm = 0; tm < 4; ++tm) {
            #pragma unroll
            for (int rr = 0; rr < 4; ++rr) {
                int row = row0 + wr * 64 + tm * 16 + (lane >> 4) * 4 + rr;
                if (row < M) {
                    P2[(size_t)row * 64 + colg] = f2bf(accL[tm][tn][rr]);
                    Out[(size_t)row * 64 + colg] = accR[tm][tn][rr] + bv;
                }
            }
        }
    }
}

extern "C" void kernel_launch(void* const* d_in, const int* in_sizes, int n_in,
                              void* d_out, int out_size, void* d_ws, size_t ws_size,
                              hipStream_t stream) {
    const float* x   = (const float*)d_in[0];
    const int*   ei  = (const int*)d_in[1];
    const float* Wl0 = (const float*)d_in[2];
    const float* Wr0 = (const float*)d_in[3];
    const float* b0  = (const float*)d_in[4];
    const float* Wl1 = (const float*)d_in[5];
    const float* Wr1 = (const float*)d_in[6];
    const float* b1  = (const float*)d_in[7];
    const float* Wl2 = (const float*)d_in[8];
    const float* Wr2 = (const float*)d_in[9];
    const float* b2  = (const float*)d_in[10];
    float* out = (float*)d_out;

    const int Nn = in_sizes[0] / 256;          // 50000
    const int E  = in_sizes[1] / 2;            // 800000
    const int Mpad = ((Nn + 127) / 128) * 128; // 50048
    const int nb = (Nn + 1023) / 1024;         // scan blocks (49)

    char* ws = (char*)d_ws;
    size_t off = 0;
    auto take = [&](size_t bytes) -> void* {
        void* p = (void*)(ws + off);
        off += (bytes + 255) & ~(size_t)255;
        return p;
    };
    int* cursor  = (int*)take((size_t)Nn * 4);      // deg after fill_pos
    int* incl    = (int*)take((size_t)Nn * 4);
    int* bsum    = (int*)take((size_t)64 * 4);
    int* row_ptr = (int*)take((size_t)(Nn + 1) * 4);
    int* col     = (int*)take((size_t)E * 4);
    int* pos     = (int*)take((size_t)E * 4);
    unsigned short* xb  = (unsigned short*)take((size_t)Mpad * 256 * 2);
    unsigned short* h1  = (unsigned short*)take((size_t)Mpad * 256 * 2);
    unsigned short* h2  = (unsigned short*)take((size_t)Mpad * 256 * 2);
    unsigned short* h3  = (unsigned short*)take((size_t)Mpad * 256 * 2);
    unsigned short* rbuf = (unsigned short*)take((size_t)Mpad * 256 * 2);
    unsigned short* p2  = (unsigned short*)take((size_t)Mpad * 64 * 2);
    unsigned short* BT0l = (unsigned short*)take((size_t)256 * 256 * 2);
    unsigned short* BT0r = (unsigned short*)take((size_t)256 * 256 * 2);
    unsigned short* BT1l = (unsigned short*)take((size_t)256 * 256 * 2);
    unsigned short* BT1r = (unsigned short*)take((size_t)256 * 256 * 2);
    unsigned short* BT2l = (unsigned short*)take((size_t)64 * 256 * 2);
    unsigned short* BT2r = (unsigned short*)take((size_t)64 * 256 * 2);
    (void)ws_size; (void)n_in; (void)out_size;

    // ---- CSR build + prep (co-gridded first kernel) ----
    hipMemsetAsync(cursor, 0, (size_t)Nn * 4, stream);
    const int n4 = Nn * 64;
    const int nPosBlk = (E + 255) / 256;
    const int prepTot = n4 + 4 * 65536 + 2 * 16384;
    const int nPrepBlk = (prepTot + 255) / 256;
    fillpos_prep_kernel<<<nPosBlk + nPrepBlk, 256, 0, stream>>>(
        ei, cursor, pos, E, nPosBlk,
        x, xb, Wl0, BT0l, Wr0, BT0r, Wl1, BT1l, Wr1, BT1r, Wl2, BT2l, Wr2, BT2r, n4);
    scan1_kernel<<<nb, 1024, 0, stream>>>(cursor, incl, bsum, Nn);
    scan3_kernel<<<(Nn + 255) / 256, 256, 0, stream>>>(incl, bsum, row_ptr, Nn, nb);
    fill_scatter_kernel<<<(E + 255) / 256, 256, 0, stream>>>(ei, pos, row_ptr, col, E);

    const int gx = Mpad / 128;
    const int aggGrid = (Nn + 3) / 4;

    // ---- layer 0: [agg(xb->h1) || r=xb@Wr0+b0] then h2=relu(h1@Wl0+r) ----
    agg_gemmR_kernel<<<aggGrid + gx, 256, 0, stream>>>(
        xb, row_ptr, col, h1, BT0r, b0, rbuf, Nn, aggGrid, Nn);
    gemmL_kernel<<<gx, 256, 0, stream>>>(h1, BT0l, rbuf, h2, Nn);
    // ---- layer 1 ----
    agg_gemmR_kernel<<<aggGrid + gx, 256, 0, stream>>>(
        h2, row_ptr, col, h1, BT1r, b1, rbuf, Nn, aggGrid, Nn);
    gemmL_kernel<<<gx, 256, 0, stream>>>(h1, BT1l, rbuf, h3, Nn);
    // ---- layer 2: dual-B GEMM then in-place agg-add ----
    gemm2_dual_kernel<<<gx, 256, 0, stream>>>(h3, BT2l, BT2r, b2, p2, out, Nn);
    agg64_add_kernel<<<aggGrid, 256, 0, stream>>>(p2, row_ptr, col, out, Nn);
}

// Round 15
// 296.492 us; speedup vs baseline: 1.6845x; 1.6845x over previous
//
#include <hip/hip_runtime.h>

// ---------------------------------------------------------------------------
// GraphSAGE 3-layer, bf16 pipeline. Round 15 = exact revert to round 13
// (296.5us, best measured). Round-14's agg||gemmR co-grid falsified:
// union-resource cost (24KB LDS + 120 VGPR on every agg block) dropped
// occupancy 66->17% and gather BW 3.7->1.3 TB/s. Heterogeneous co-grid only
// works when both paths are resource-light.
// Pipeline: fillpos+prep (co-grid) -> scan -> scatter ->
//   L0: agg256; gemm(BM128xBN256) -> L1: same -> L2: dual-B gemm + agg64-add.
// agg256 at measured structural floor (~55us; invariant across 6 variants).
// ---------------------------------------------------------------------------

typedef short bf16x8 __attribute__((ext_vector_type(8)));
typedef float f32x4 __attribute__((ext_vector_type(4)));

__device__ __forceinline__ unsigned short f2bf(float f) {
    unsigned int b = __float_as_uint(f);
    b += 0x7fffu + ((b >> 16) & 1u);
    return (unsigned short)(b >> 16);
}
__device__ __forceinline__ float bflo(unsigned int u) { return __uint_as_float(u << 16); }
__device__ __forceinline__ float bfhi(unsigned int u) { return __uint_as_float(u & 0xffff0000u); }

__device__ __forceinline__ void gload_lds16(const void* g, void* l) {
    __builtin_amdgcn_global_load_lds(
        (const __attribute__((address_space(1))) void*)g,
        (__attribute__((address_space(3))) void*)l, 16, 0, 0);
}

// ---------------- combined fill_pos + prep ----------------
__global__ void fillpos_prep_kernel(
        const int* __restrict__ ei, int* __restrict__ cursor, int* __restrict__ pos,
        int E, int nPosBlk,
        const float* __restrict__ x, unsigned short* __restrict__ xb,
        const float* __restrict__ Wl0, const float* __restrict__ Wr0,
        unsigned short* __restrict__ BT0,
        const float* __restrict__ Wl1, const float* __restrict__ Wr1,
        unsigned short* __restrict__ BT1,
        const float* __restrict__ Wl2, unsigned short* __restrict__ BT2l,
        const float* __restrict__ Wr2, unsigned short* __restrict__ BT2r,
        int n4) {
    if (blockIdx.x < nPosBlk) {
        int e = blockIdx.x * 256 + threadIdx.x;
        if (e < E) pos[e] = atomicAdd(&cursor[ei[E + e]], 1);
        return;
    }
    int t = (blockIdx.x - nPosBlk) * 256 + threadIdx.x;
    if (t < n4) {
        float4 v = ((const float4*)x)[t];
        ushort4 o;
        o.x = f2bf(v.x); o.y = f2bf(v.y); o.z = f2bf(v.z); o.w = f2bf(v.w);
        ((ushort4*)xb)[t] = o;
        return;
    }
    t -= n4;
    if (t < 131072) {           // BT0: [256 cols][512 k]
        int k = t >> 8, n = t & 255;
        float v = (k < 256) ? Wl0[(size_t)k * 256 + n] : Wr0[(size_t)(k - 256) * 256 + n];
        BT0[(size_t)n * 512 + k] = f2bf(v);
        return;
    }
    t -= 131072;
    if (t < 131072) {           // BT1
        int k = t >> 8, n = t & 255;
        float v = (k < 256) ? Wl1[(size_t)k * 256 + n] : Wr1[(size_t)(k - 256) * 256 + n];
        BT1[(size_t)n * 512 + k] = f2bf(v);
        return;
    }
    t -= 131072;
    if (t < 16384) {            // BT2l: [64 cols][256 k]
        int k = t >> 6, n = t & 63;
        BT2l[(size_t)n * 256 + k] = f2bf(Wl2[(size_t)k * 64 + n]);
        return;
    }
    t -= 16384;
    if (t < 16384) {            // BT2r
        int k = t >> 6, n = t & 63;
        BT2r[(size_t)n * 256 + k] = f2bf(Wr2[(size_t)k * 64 + n]);
    }
}

// ---------------- CSR scan ----------------
__global__ __launch_bounds__(1024) void scan1_kernel(
        const int* __restrict__ deg, int* __restrict__ incl, int* __restrict__ bsum, int n) {
    __shared__ int wsum[16];
    __shared__ int woff[16];
    const int tid = threadIdx.x, lane = tid & 63, wid = tid >> 6;
    int i = blockIdx.x * 1024 + tid;
    int x = (i < n) ? deg[i] : 0;
    #pragma unroll
    for (int off = 1; off < 64; off <<= 1) {
        int t = __shfl_up(x, off, 64);
        if (lane >= off) x += t;
    }
    if (lane == 63) wsum[wid] = x;
    __syncthreads();
    if (tid == 0) {
        int s = 0;
        #pragma unroll
        for (int w = 0; w < 16; ++w) { woff[w] = s; s += wsum[w]; }
        bsum[blockIdx.x] = s;
    }
    __syncthreads();
    if (i < n) incl[i] = x + woff[wid];
}

// scan2+scan3 merged: block covers 256 nodes; chunk = b>>2
__global__ void scan3_kernel(const int* __restrict__ incl, const int* __restrict__ bsum,
                             int* __restrict__ row_ptr, int n, int nb) {
    __shared__ int off_s;
    const int chunk = blockIdx.x >> 2;
    if (threadIdx.x < 64) {
        int lane = threadIdx.x;
        int v = (lane < chunk && lane < nb) ? bsum[lane] : 0;
        #pragma unroll
        for (int m = 1; m < 64; m <<= 1) v += __shfl_xor(v, m, 64);
        if (lane == 0) off_s = v;
    }
    __syncthreads();
    int i = blockIdx.x * 256 + threadIdx.x;
    if (i == 0) row_ptr[0] = 0;
    if (i < n) row_ptr[i + 1] = incl[i] + off_s;
}

__global__ void fill_scatter_kernel(const int* __restrict__ ei, const int* __restrict__ pos,
                                    const int* __restrict__ row_ptr, int* __restrict__ col, int E) {
    int e = blockIdx.x * blockDim.x + threadIdx.x;
    if (e < E) {
        int d = ei[E + e];
        col[row_ptr[d] + pos[e]] = ei[e];
    }
}

// ---------------- aggregation, 256-dim (proven structure) ----------------
__global__ __launch_bounds__(256) void aggregate256_kernel(
        const unsigned short* __restrict__ h, const int* __restrict__ row_ptr,
        const int* __restrict__ col, unsigned short* __restrict__ agg, int n) {
    int node = blockIdx.x * 4 + (threadIdx.x >> 6);
    int lane = threadIdx.x & 63;
    if (node >= n) return;
    const int start = row_ptr[node], end = row_ptr[node + 1];
    const int half = lane >> 5;
    const int fo = (lane & 31) * 8;     // 8 bf16 per lane
    float a[8] = {0.f, 0.f, 0.f, 0.f, 0.f, 0.f, 0.f, 0.f};
    int eb = start;
    for (; eb + 4 <= end; eb += 4) {
        int e0 = eb + half, e1 = eb + 2 + half;
        uint4 v0 = *(const uint4*)(h + (size_t)col[e0] * 256 + fo);
        uint4 v1 = *(const uint4*)(h + (size_t)col[e1] * 256 + fo);
        a[0] += bflo(v0.x) + bflo(v1.x); a[1] += bfhi(v0.x) + bfhi(v1.x);
        a[2] += bflo(v0.y) + bflo(v1.y); a[3] += bfhi(v0.y) + bfhi(v1.y);
        a[4] += bflo(v0.z) + bflo(v1.z); a[5] += bfhi(v0.z) + bfhi(v1.z);
        a[6] += bflo(v0.w) + bflo(v1.w); a[7] += bfhi(v0.w) + bfhi(v1.w);
    }
    for (; eb < end; eb += 2) {
        int e = eb + half;
        if (e < end) {
            uint4 v = *(const uint4*)(h + (size_t)col[e] * 256 + fo);
            a[0] += bflo(v.x); a[1] += bfhi(v.x);
            a[2] += bflo(v.y); a[3] += bfhi(v.y);
            a[4] += bflo(v.z); a[5] += bfhi(v.z);
            a[6] += bflo(v.w); a[7] += bfhi(v.w);
        }
    }
    #pragma unroll
    for (int i = 0; i < 8; ++i) a[i] += __shfl_xor(a[i], 32, 64);
    int d = end - start;
    float inv = 1.0f / (float)(d > 1 ? d : 1);
    if (lane < 32) {
        ushort4 o0, o1;
        o0.x = f2bf(a[0] * inv); o0.y = f2bf(a[1] * inv);
        o0.z = f2bf(a[2] * inv); o0.w = f2bf(a[3] * inv);
        o1.x = f2bf(a[4] * inv); o1.y = f2bf(a[5] * inv);
        o1.z = f2bf(a[6] * inv); o1.w = f2bf(a[7] * inv);
        *(ushort4*)(agg + (size_t)node * 256 + fo) = o0;
        *(ushort4*)(agg + (size_t)node * 256 + fo + 4) = o1;
    }
}

// ---------------- aggregation, 64-dim, in-place add into out ----------------
__global__ __launch_bounds__(256) void agg64_add_kernel(
        const unsigned short* __restrict__ p, const int* __restrict__ row_ptr,
        const int* __restrict__ col, float* __restrict__ out, int n) {
    int node = blockIdx.x * 4 + (threadIdx.x >> 6);
    int lane = threadIdx.x & 63;
    if (node >= n) return;
    const int start = row_ptr[node], end = row_ptr[node + 1];
    const int g = lane >> 4;
    const int fo = (lane & 15) * 4;
    float a0 = 0.f, a1 = 0.f, a2 = 0.f, a3 = 0.f;
    int eb = start;
    for (; eb + 8 <= end; eb += 8) {
        int e0 = eb + g, e1 = eb + 4 + g;
        uint2 v0 = *(const uint2*)(p + (size_t)col[e0] * 64 + fo);
        uint2 v1 = *(const uint2*)(p + (size_t)col[e1] * 64 + fo);
        a0 += bflo(v0.x) + bflo(v1.x); a1 += bfhi(v0.x) + bfhi(v1.x);
        a2 += bflo(v0.y) + bflo(v1.y); a3 += bfhi(v0.y) + bfhi(v1.y);
    }
    for (; eb < end; eb += 4) {
        int e = eb + g;
        if (e < end) {
            uint2 v = *(const uint2*)(p + (size_t)col[e] * 64 + fo);
            a0 += bflo(v.x); a1 += bfhi(v.x);
            a2 += bflo(v.y); a3 += bfhi(v.y);
        }
    }
    #pragma unroll
    for (int m = 16; m <= 32; m <<= 1) {
        a0 += __shfl_xor(a0, m, 64);
        a1 += __shfl_xor(a1, m, 64);
        a2 += __shfl_xor(a2, m, 64);
        a3 += __shfl_xor(a3, m, 64);
    }
    int d = end - start;
    float inv = 1.0f / (float)(d > 1 ? d : 1);
    if (lane < 16) {
        float* dst = out + (size_t)node * 64 + fo;
        float4 base = *(float4*)dst;
        float4 o = make_float4(base.x + a0 * inv, base.y + a1 * inv,
                               base.z + a2 * inv, base.w + a3 * inv);
        *(float4*)dst = o;
    }
}

// ---------------- layers 0/1 MFMA GEMM (round-11 proven config) ----------
template<int NKS, int NT, bool RELU>
__global__ __launch_bounds__(256, 2) void gemm_mfma_kernel(
        const unsigned short* __restrict__ A0, const unsigned short* __restrict__ A1,
        const unsigned short* __restrict__ BT, const float* __restrict__ bias,
        unsigned short* __restrict__ Cout, int M, int Nc) {
    constexpr int BN = NT * 32;
    constexpr int KB = NKS * 32;
    __shared__ unsigned short As[128 * 32];
    __shared__ unsigned short Bs[BN * 32];
    const int tid = threadIdx.x;
    const int lane = tid & 63;
    const int wid = tid >> 6;
    const int wr = wid >> 1, wc = wid & 1;
    const int row0 = blockIdx.x * 128;
    const int col0 = blockIdx.y * BN;

    f32x4 acc[4][NT];
    #pragma unroll
    for (int i = 0; i < 4; ++i)
        #pragma unroll
        for (int j = 0; j < NT; ++j) acc[i][j] = (f32x4){0.f, 0.f, 0.f, 0.f};

    const int rA = tid >> 2;
    const int kc = (tid & 3) * 8;

    for (int ks = 0; ks < NKS; ++ks) {
        const unsigned short* Asrc = (ks < 8) ? A0 : A1;
        const int ka = (ks & 7) * 32;
        #pragma unroll
        for (int i = 0; i < 2; ++i) {
            const unsigned short* g = Asrc + (size_t)(row0 + rA + i * 64) * 256 + ka + kc;
            gload_lds16(g, As + (size_t)i * 2048 + tid * 8);
        }
        #pragma unroll
        for (int i = 0; i < NT / 2; ++i) {
            const unsigned short* g = BT + (size_t)(col0 + rA + i * 64) * KB + ks * 32 + kc;
            gload_lds16(g, Bs + (size_t)i * 2048 + tid * 8);
        }
        __syncthreads();

        bf16x8 a[4], b[NT];
        #pragma unroll
        for (int tm = 0; tm < 4; ++tm)
            a[tm] = *(const bf16x8*)&As[(wr * 64 + tm * 16 + (lane & 15)) * 32 + (lane >> 4) * 8];
        #pragma unroll
        for (int tn = 0; tn < NT; ++tn)
            b[tn] = *(const bf16x8*)&Bs[(wc * NT * 16 + tn * 16 + (lane & 15)) * 32 + (lane >> 4) * 8];
        #pragma unroll
        for (int tm = 0; tm < 4; ++tm)
            #pragma unroll
            for (int tn = 0; tn < NT; ++tn)
                acc[tm][tn] = __builtin_amdgcn_mfma_f32_16x16x32_bf16(a[tm], b[tn], acc[tm][tn], 0, 0, 0);
        __syncthreads();
    }

    const int cb = col0 + wc * NT * 16;
    #pragma unroll
    for (int tn = 0; tn < NT; ++tn) {
        int colg = cb + tn * 16 + (lane & 15);
        float bv = bias[colg];
        #pragma unroll
        for (int tm = 0; tm < 4; ++tm) {
            #pragma unroll
            for (int r = 0; r < 4; ++r) {
                int row = row0 + wr * 64 + tm * 16 + (lane >> 4) * 4 + r;
                if (row < M) {
                    float v = acc[tm][tn][r] + bv;
                    if (RELU) v = fmaxf(v, 0.f);
                    Cout[(size_t)row * Nc + colg] = f2bf(v);
                }
            }
        }
    }
}

// ---------------- layer-2 dual-B GEMM (BM=128) ----------------
__global__ __launch_bounds__(256, 2) void gemm2_dual_kernel(
        const unsigned short* __restrict__ A,     // h3 [Mpad][256]
        const unsigned short* __restrict__ BTl,   // [64][256]
        const unsigned short* __restrict__ BTr,   // [64][256]
        const float* __restrict__ bias,           // [64]
        unsigned short* __restrict__ P2,          // [Mpad][64] bf16
        float* __restrict__ Out, int M) {
    __shared__ unsigned short As[128 * 32];
    __shared__ unsigned short Bl[64 * 32];
    __shared__ unsigned short Br[64 * 32];
    const int tid = threadIdx.x;
    const int lane = tid & 63;
    const int wid = tid >> 6;
    const int wr = wid >> 1, wc = wid & 1;
    const int row0 = blockIdx.x * 128;

    f32x4 accL[4][2], accR[4][2];
    #pragma unroll
    for (int i = 0; i < 4; ++i)
        #pragma unroll
        for (int j = 0; j < 2; ++j) {
            accL[i][j] = (f32x4){0.f, 0.f, 0.f, 0.f};
            accR[i][j] = (f32x4){0.f, 0.f, 0.f, 0.f};
        }

    const int rA = tid >> 2;
    const int kc = (tid & 3) * 8;

    for (int ks = 0; ks < 8; ++ks) {
        const int ka = ks * 32;
        #pragma unroll
        for (int i = 0; i < 2; ++i) {
            const unsigned short* g = A + (size_t)(row0 + rA + i * 64) * 256 + ka + kc;
            gload_lds16(g, As + (size_t)i * 2048 + tid * 8);
        }
        gload_lds16(BTl + (size_t)rA * 256 + ka + kc, Bl + tid * 8);
        gload_lds16(BTr + (size_t)rA * 256 + ka + kc, Br + tid * 8);
        __syncthreads();

        bf16x8 a[4], bl[2], br[2];
        #pragma unroll
        for (int tm = 0; tm < 4; ++tm)
            a[tm] = *(const bf16x8*)&As[(wr * 64 + tm * 16 + (lane & 15)) * 32 + (lane >> 4) * 8];
        #pragma unroll
        for (int tn = 0; tn < 2; ++tn) {
            int bi = (wc * 32 + tn * 16 + (lane & 15)) * 32 + (lane >> 4) * 8;
            bl[tn] = *(const bf16x8*)&Bl[bi];
            br[tn] = *(const bf16x8*)&Br[bi];
        }
        #pragma unroll
        for (int tm = 0; tm < 4; ++tm)
            #pragma unroll
            for (int tn = 0; tn < 2; ++tn) {
                accL[tm][tn] = __builtin_amdgcn_mfma_f32_16x16x32_bf16(a[tm], bl[tn], accL[tm][tn], 0, 0, 0);
                accR[tm][tn] = __builtin_amdgcn_mfma_f32_16x16x32_bf16(a[tm], br[tn], accR[tm][tn], 0, 0, 0);
            }
        __syncthreads();
    }

    #pragma unroll
    for (int tn = 0; tn < 2; ++tn) {
        int colg = wc * 32 + tn * 16 + (lane & 15);
        float bv = bias[colg];
        #pragma unroll
        for (int tm = 0; tm < 4; ++tm) {
            #pragma unroll
            for (int r = 0; r < 4; ++r) {
                int row = row0 + wr * 64 + tm * 16 + (lane >> 4) * 4 + r;
                if (row < M) {
                    P2[(size_t)row * 64 + colg] = f2bf(accL[tm][tn][r]);
                    Out[(size_t)row * 64 + colg] = accR[tm][tn][r] + bv;
                }
            }
        }
    }
}

extern "C" void kernel_launch(void* const* d_in, const int* in_sizes, int n_in,
                              void* d_out, int out_size, void* d_ws, size_t ws_size,
                              hipStream_t stream) {
    const float* x   = (const float*)d_in[0];
    const int*   ei  = (const int*)d_in[1];
    const float* Wl0 = (const float*)d_in[2];
    const float* Wr0 = (const float*)d_in[3];
    const float* b0  = (const float*)d_in[4];
    const float* Wl1 = (const float*)d_in[5];
    const float* Wr1 = (const float*)d_in[6];
    const float* b1  = (const float*)d_in[7];
    const float* Wl2 = (const float*)d_in[8];
    const float* Wr2 = (const float*)d_in[9];
    const float* b2  = (const float*)d_in[10];
    float* out = (float*)d_out;

    const int Nn = in_sizes[0] / 256;          // 50000
    const int E  = in_sizes[1] / 2;            // 800000
    const int Mpad = ((Nn + 127) / 128) * 128; // 50048
    const int nb = (Nn + 1023) / 1024;         // scan blocks (49)

    char* ws = (char*)d_ws;
    size_t off = 0;
    auto take = [&](size_t bytes) -> void* {
        void* p = (void*)(ws + off);
        off += (bytes + 255) & ~(size_t)255;
        return p;
    };
    int* cursor  = (int*)take((size_t)Nn * 4);      // deg after fill_pos
    int* incl    = (int*)take((size_t)Nn * 4);
    int* bsum    = (int*)take((size_t)64 * 4);
    int* row_ptr = (int*)take((size_t)(Nn + 1) * 4);
    int* col     = (int*)take((size_t)E * 4);
    int* pos     = (int*)take((size_t)E * 4);
    unsigned short* xb  = (unsigned short*)take((size_t)Mpad * 256 * 2);
    unsigned short* h1  = (unsigned short*)take((size_t)Mpad * 256 * 2);
    unsigned short* h2  = (unsigned short*)take((size_t)Mpad * 256 * 2);
    unsigned short* h3  = (unsigned short*)take((size_t)Mpad * 256 * 2);
    unsigned short* p2  = (unsigned short*)take((size_t)Mpad * 64 * 2);
    unsigned short* BT0  = (unsigned short*)take((size_t)256 * 512 * 2);
    unsigned short* BT1  = (unsigned short*)take((size_t)256 * 512 * 2);
    unsigned short* BT2l = (unsigned short*)take((size_t)64 * 256 * 2);
    unsigned short* BT2r = (unsigned short*)take((size_t)64 * 256 * 2);
    (void)ws_size; (void)n_in; (void)out_size;

    // ---- CSR build + prep (co-gridded first kernel) ----
    hipMemsetAsync(cursor, 0, (size_t)Nn * 4, stream);
    const int n4 = Nn * 64;
    const int nPosBlk = (E + 255) / 256;
    const int prepTot = n4 + 131072 + 131072 + 16384 + 16384;
    const int nPrepBlk = (prepTot + 255) / 256;
    fillpos_prep_kernel<<<nPosBlk + nPrepBlk, 256, 0, stream>>>(
        ei, cursor, pos, E, nPosBlk,
        x, xb, Wl0, Wr0, BT0, Wl1, Wr1, BT1, Wl2, BT2l, Wr2, BT2r, n4);
    scan1_kernel<<<nb, 1024, 0, stream>>>(cursor, incl, bsum, Nn);
    scan3_kernel<<<(Nn + 255) / 256, 256, 0, stream>>>(incl, bsum, row_ptr, Nn, nb);
    fill_scatter_kernel<<<(E + 255) / 256, 256, 0, stream>>>(ei, pos, row_ptr, col, E);

    const int gx = Mpad / 128;
    const int aggGrid = (Nn + 3) / 4;

    // ---- layer 0 ----
    aggregate256_kernel<<<aggGrid, 256, 0, stream>>>(xb, row_ptr, col, h1, Nn);
    gemm_mfma_kernel<16, 8, true><<<dim3(gx, 1), 256, 0, stream>>>(
        h1, xb, BT0, b0, h2, Nn, 256);
    // ---- layer 1 ----
    aggregate256_kernel<<<aggGrid, 256, 0, stream>>>(h2, row_ptr, col, h1, Nn);
    gemm_mfma_kernel<16, 8, true><<<dim3(gx, 1), 256, 0, stream>>>(
        h1, h2, BT1, b1, h3, Nn, 256);
    // ---- layer 2: dual-B GEMM then in-place agg-add ----
    gemm2_dual_kernel<<<gx, 256, 0, stream>>>(h3, BT2l, BT2r, b2, p2, out, Nn);
    agg64_add_kernel<<<aggGrid, 256, 0, stream>>>(p2, row_ptr, col, out, Nn);
}